// Round 10
// baseline (154.327 us; speedup 1.0000x reference)
//
#include <hip/hip_runtime.h>
#include <hip/hip_fp16.h>

#define TPB 256
#define NEG_SLOPE 0.2f
#define B1 256          // blocks for hist/place passes
#define DPB 512         // dsts per bucket
#define MAXNB 128       // max buckets

// ---------- helpers ----------
__device__ __forceinline__ int getIdx(const void* p, int is32, long long i) {
  return is32 ? ((const int*)p)[i] : (int)((const long long*)p)[i];
}

// ---------- CSR stage 1: per-block bucket histograms (inline dtype sniff) ----------
__global__ __launch_bounds__(TPB) void k_histA(
    const void* __restrict__ ei, int E, int Etot,
    int* __restrict__ histA, int NB, int CH) {
  __shared__ int lh[MAXNB];
  __shared__ int sflag;
  int b = blockIdx.x, tid = threadIdx.x;
  for (int i = tid; i < NB; i += TPB) lh[i] = 0;
  if (tid < 64) {  // wave 0: sniff int32 vs int64 storage (ids < 2^31)
    const unsigned long long* p = (const unsigned long long*)ei;
    unsigned long long m = __ballot(tid < E && p[tid] > 0xFFFFFFFFULL);
    if (tid == 0) sflag = (m != 0ULL) ? 1 : 0;
  }
  __syncthreads();
  int f = sflag;
  int beg = b * CH, end = min(beg + CH, Etot);
  for (int e = beg + tid; e < end; e += TPB) {
    int d = (e < E) ? getIdx(ei, f, (long long)E + e) : e - E;
    atomicAdd(&lh[d / DPB], 1);
  }
  __syncthreads();
  for (int i = tid; i < NB; i += TPB) histA[b * NB + i] = lh[i];  // [block][bucket]
}

// ---------- CSR stage 2: prefix bases (single block) ----------
__global__ __launch_bounds__(TPB) void k_scanA(
    const int* __restrict__ histA, int* __restrict__ blockBase,
    int* __restrict__ bucketBase, int NB) {
  __shared__ int sh[TPB];
  int t = threadIdx.x;
  int tot = 0;
  if (t < NB) {
    int run = 0;
    for (int b = 0; b < B1; ++b) {           // coalesced: histA[b*NB + t]
      int v = histA[b * NB + t];
      blockBase[b * NB + t] = run;           // intra-bucket prefix over blocks
      run += v;
    }
    tot = run;
  }
  sh[t] = tot;
  __syncthreads();
  for (int off = 1; off < TPB; off <<= 1) {
    int v = (t >= off) ? sh[t - off] : 0;
    __syncthreads();
    sh[t] += v;
    __syncthreads();
  }
  if (t < NB) bucketBase[t] = sh[t] - tot;   // exclusive
  if (t == TPB - 1) bucketBase[NB] = sh[TPB - 1];  // == Etot
}

// ---------- CSR stage 3: place (src,dst) int2 pairs grouped by bucket ----------
__global__ __launch_bounds__(TPB) void k_placeB(
    const void* __restrict__ ei, int E, int Etot,
    const int* __restrict__ blockBase, const int* __restrict__ bucketBase,
    int2* __restrict__ pairs, int NB, int CH) {
  __shared__ int cur[MAXNB];
  __shared__ int sflag;
  int b = blockIdx.x, tid = threadIdx.x;
  for (int i = tid; i < NB; i += TPB) cur[i] = blockBase[b * NB + i] + bucketBase[i];
  if (tid < 64) {
    const unsigned long long* p = (const unsigned long long*)ei;
    unsigned long long m = __ballot(tid < E && p[tid] > 0xFFFFFFFFULL);
    if (tid == 0) sflag = (m != 0ULL) ? 1 : 0;
  }
  __syncthreads();
  int f = sflag;
  int beg = b * CH, end = min(beg + CH, Etot);
  for (int e = beg + tid; e < end; e += TPB) {
    int s, d;
    if (e < E) {
      s = getIdx(ei, f, e);
      d = getIdx(ei, f, (long long)E + e);
    } else {
      s = d = e - E;
    }
    int pos = atomicAdd(&cur[d / DPB], 1);
    pairs[pos] = make_int2(s, d);
  }
}

// ---------- CSR stage 4: per-bucket hist+scan -> rowptr, then place csr_src ----------
__global__ __launch_bounds__(DPB) void k_bucket(
    const int2* __restrict__ pairs, const int* __restrict__ bucketBase,
    int* __restrict__ rowptr, int* __restrict__ csr_src, int N, int Etot) {
  __shared__ int cnt[DPB];
  __shared__ int sc[DPB];
  int g = blockIdx.x, tid = threadIdx.x;
  int base = g * DPB;
  int nd = N - base; if (nd > DPB) nd = DPB;
  cnt[tid] = 0;
  __syncthreads();
  int beg = bucketBase[g], end = bucketBase[g + 1];
  for (int j = beg + tid; j < end; j += DPB)
    atomicAdd(&cnt[pairs[j].y & (DPB - 1)], 1);
  __syncthreads();
  sc[tid] = cnt[tid];
  __syncthreads();
  for (int off = 1; off < DPB; off <<= 1) {
    int v = (tid >= off) ? sc[tid - off] : 0;
    __syncthreads();
    sc[tid] += v;
    __syncthreads();
  }
  int excl = beg + sc[tid] - cnt[tid];
  if (tid < nd) rowptr[base + tid] = excl;
  if (g == 0 && tid == 0) rowptr[N] = Etot;
  __syncthreads();
  cnt[tid] = excl;  // becomes cursor
  __syncthreads();
  for (int j = beg + tid; j < end; j += DPB) {
    int2 p = pairs[j];
    int pos = atomicAdd(&cnt[p.y & (DPB - 1)], 1);
    csr_src[pos] = p.x;
  }
}

// ---------- layer 1: h1 = x @ W1 (fp16 out), fused alpha dots ----------
__global__ __launch_bounds__(TPB) void k_gemm1(
    const float* __restrict__ x, const float* __restrict__ W1,
    const float* __restrict__ aS, const float* __restrict__ aD,
    __half* __restrict__ h1, float* __restrict__ asrc, float* __restrict__ adst, int N) {
  __shared__ float Wl[64 * 64];
  __shared__ float xr[4][64];
  int t = threadIdx.x;
  for (int i = t; i < 64 * 64; i += TPB) Wl[i] = W1[i];
  int w = t >> 6, lane = t & 63;
  int node = blockIdx.x * 4 + w;
  if (node < N) xr[w][lane] = x[(size_t)node * 64 + lane];
  __syncthreads();
  if (node >= N) return;
  float acc = 0.f;
#pragma unroll
  for (int k = 0; k < 64; ++k) acc = fmaf(xr[w][k], Wl[k * 64 + lane], acc);
  h1[(size_t)node * 64 + lane] = __float2half(acc);
  float vs = acc * aS[lane];
  float vd = acc * aD[lane];
#pragma unroll
  for (int m = 16; m >= 1; m >>= 1) {
    vs += __shfl_xor(vs, m, 64);
    vd += __shfl_xor(vd, m, 64);
  }
  if ((lane & 31) == 0) {
    asrc[node * 2 + (lane >> 5)] = vs;
    adst[node * 2 + (lane >> 5)] = vd;
  }
}

// ---------- fused layer-1 gather + layer-2 linear, LDS-op-minimized ----------
// Lane c=lane&31 owns feature pair {2c,2c+1}; eh=lane>>5 is edge parity.
// Phase 1: lane i computes edge i's weights (parallel id/alpha loads).
// Phase 2: 2 edges/iter via coalesced half2 loads; cross-edge reduce = 2 shfls.
// Layer-2 dot: W2 held in 32 registers/lane; row broadcast via 8 ds_read_b128.
__global__ __launch_bounds__(TPB) void k_gather1f(
    const int* __restrict__ rowptr, const int* __restrict__ csr_src,
    const float* __restrict__ as1, const float* __restrict__ ad1,
    const __half* __restrict__ h1, const float* __restrict__ b1,
    const float* __restrict__ W2, const float* __restrict__ aS2,
    const float* __restrict__ aD2,
    __half* __restrict__ h2, float* __restrict__ as2, float* __restrict__ ad2, int N) {
  __shared__ int   sSid[4][64];
  __shared__ float sWp[4][128];
  __shared__ float rowBuf[4][64];
  int t = threadIdx.x;
  int w = t >> 6, lane = t & 63;
  int node = blockIdx.x * 4 + w;
  if (node >= N) return;

  int c = lane & 31;        // feature-pair owner (feats 2c, 2c+1); also out-channel
  int eh = lane >> 5;       // edge parity / k-range half
  int head = c >> 4;        // head of feats 2c,2c+1
  // per-lane preloads (L2-cached)
  float2 b1v = ((const float2*)b1)[c];
  float w2r[32];
#pragma unroll
  for (int k = 0; k < 32; ++k) w2r[k] = W2[(eh * 32 + k) * 32 + c];
  float aS2v = aS2[c], aD2v = aD2[c];

  float2 adv = *(const float2*)(ad1 + (size_t)node * 2);
  int beg = rowptr[node], end = rowptr[node + 1];
  float a0 = 0.f, a1 = 0.f, d0L = 0.f, d1L = 0.f;
  for (int chunk = beg; chunk < end; chunk += 64) {
    int m = end - chunk; if (m > 64) m = 64;
    if (lane < m) {                      // phase 1: up to 64 edges in parallel
      int sid = csr_src[chunk + lane];
      float2 av = *(const float2*)(as1 + (size_t)sid * 2);
      float v0 = av.x + adv.x, v1 = av.y + adv.y;
      v0 = v0 > 0.f ? v0 : NEG_SLOPE * v0;
      v1 = v1 > 0.f ? v1 : NEG_SLOPE * v1;
      float w0 = __expf(v0), w1 = __expf(v1);
      d0L += w0; d1L += w1;
      sSid[w][lane] = sid;
      *(float2*)&sWp[w][lane * 2] = make_float2(w0, w1);
    }
    // same-wave LDS handoff (lockstep)
    for (int j = eh; j < m; j += 2) {    // phase 2: 2 edges/iter
      int s = sSid[w][j];
      float wgt = sWp[w][j * 2 + head];
      __half2 hv = *((const __half2*)(h1 + (size_t)s * 64) + c);
      float2 f = __half22float2(hv);
      a0 = fmaf(wgt, f.x, a0);
      a1 = fmaf(wgt, f.y, a1);
    }
  }
  a0 += __shfl_xor(a0, 32, 64);          // combine even/odd edge partials
  a1 += __shfl_xor(a1, 32, 64);
#pragma unroll
  for (int m2 = 1; m2 <= 32; m2 <<= 1) { // denominator: full-wave reduce
    d0L += __shfl_xor(d0L, m2, 64);
    d1L += __shfl_xor(d1L, m2, 64);
  }
  float inv = 1.f / ((head == 0 ? d0L : d1L) + 1e-16f);
  float o0 = fmaf(a0, inv, b1v.x);
  float o1 = fmaf(a1, inv, b1v.y);
  o0 = o0 > 0.f ? o0 : 0.f;
  o1 = o1 > 0.f ? o1 : 0.f;
  if (eh == 0) *(float2*)&rowBuf[w][c * 2] = make_float2(o0, o1);
  // layer-2 dot: row broadcast from LDS (b128), W2 from registers
  float acc2 = 0.f;
#pragma unroll
  for (int kk = 0; kk < 8; ++kk) {
    float4 rv = *(const float4*)&rowBuf[w][eh * 32 + kk * 4];
    acc2 = fmaf(rv.x, w2r[kk * 4 + 0], acc2);
    acc2 = fmaf(rv.y, w2r[kk * 4 + 1], acc2);
    acc2 = fmaf(rv.z, w2r[kk * 4 + 2], acc2);
    acc2 = fmaf(rv.w, w2r[kk * 4 + 3], acc2);
  }
  acc2 += __shfl_xor(acc2, 32, 64);      // combine k-range halves
  if (eh == 0) h2[(size_t)node * 32 + c] = __float2half(acc2);
  float vs = acc2 * aS2v;
  float vd = acc2 * aD2v;
#pragma unroll
  for (int m2 = 16; m2 >= 1; m2 >>= 1) {
    vs += __shfl_xor(vs, m2, 64);
    vd += __shfl_xor(vd, m2, 64);
  }
  if (lane == 0) {
    as2[node] = vs;
    ad2[node] = vd;
  }
}

// ---------- layer 2 gather: feature-pair per lane, 4 edges/iter ----------
__global__ __launch_bounds__(TPB) void k_gather2(
    const int* __restrict__ rowptr, const int* __restrict__ csr_src,
    const float* __restrict__ as2, const float* __restrict__ ad2,
    const __half* __restrict__ h2, const float* __restrict__ b,
    float* __restrict__ out, int N) {
  __shared__ int   sS[4][64];
  __shared__ float sWv[4][64];
  int t = threadIdx.x;
  int w = t >> 6;
  int wid = (int)((blockIdx.x * (unsigned)TPB + t) >> 6);
  int lane = t & 63;
  if (wid >= N) return;
  int c = lane & 15;     // feats 2c, 2c+1
  int eq = lane >> 4;    // edge slot (0..3)
  float2 bv = ((const float2*)b)[c];
  float ad = ad2[wid];
  int beg = rowptr[wid], end = rowptr[wid + 1];
  float a0 = 0.f, a1 = 0.f, dL = 0.f;
  for (int chunk = beg; chunk < end; chunk += 64) {
    int m = end - chunk; if (m > 64) m = 64;
    if (lane < m) {                      // phase 1
      int sid = csr_src[chunk + lane];
      float v = as2[sid] + ad;
      v = v > 0.f ? v : NEG_SLOPE * v;
      float wv = __expf(v);
      dL += wv;
      sS[w][lane] = sid;
      sWv[w][lane] = wv;
    }
    for (int j = eq; j < m; j += 4) {    // phase 2: 4 edges/iter
      int s = sS[w][j];
      float wgt = sWv[w][j];
      __half2 hv = *((const __half2*)(h2 + (size_t)s * 32) + c);
      float2 f = __half22float2(hv);
      a0 = fmaf(wgt, f.x, a0);
      a1 = fmaf(wgt, f.y, a1);
    }
  }
  a0 += __shfl_xor(a0, 16, 64); a0 += __shfl_xor(a0, 32, 64);
  a1 += __shfl_xor(a1, 16, 64); a1 += __shfl_xor(a1, 32, 64);
#pragma unroll
  for (int m2 = 1; m2 <= 32; m2 <<= 1) dL += __shfl_xor(dL, m2, 64);
  if (eq == 0) {
    float inv = 1.f / (dL + 1e-16f);
    float2 o = make_float2(fmaf(a0, inv, bv.x), fmaf(a1, inv, bv.y));
    *(float2*)(out + (size_t)wid * 32 + c * 2) = o;
  }
}

extern "C" void kernel_launch(void* const* d_in, const int* in_sizes, int n_in,
                              void* d_out, int out_size, void* d_ws, size_t ws_size,
                              hipStream_t stream) {
  const float* x   = (const float*)d_in[0];
  const void*  ei  = d_in[1];
  const float* W1  = (const float*)d_in[2];
  const float* aS1 = (const float*)d_in[3];
  const float* aD1 = (const float*)d_in[4];
  const float* b1  = (const float*)d_in[5];
  const float* W2  = (const float*)d_in[6];
  const float* aS2 = (const float*)d_in[7];
  const float* aD2 = (const float*)d_in[8];
  const float* b2  = (const float*)d_in[9];
  float* out = (float*)d_out;

  int N = in_sizes[0] / 64;
  int E = in_sizes[1] / 2;
  int Etot = E + N;
  int NB = (N + DPB - 1) / DPB;         // dst buckets
  int CH = (Etot + B1 - 1) / B1;        // edges per hist/place block

  float* W = (float*)d_ws;
  size_t o = 0;
  __half* h1 = (__half*)(W + o); o += (size_t)N * 32;   // N*64 halfs
  // pairs (int2, Etot) shares storage with h2 (N*32 halfs): disjoint lifetimes
  size_t regB = (size_t)(2 * (size_t)Etot > (size_t)N * 16 ? 2 * (size_t)Etot : (size_t)N * 16);
  int2* pairs = (int2*)(W + o);
  __half* h2  = (__half*)(W + o);
  o += regB;
  float* as1  = W + o; o += (size_t)N * 2;
  float* ad1  = W + o; o += (size_t)N * 2;
  float* as2  = W + o; o += (size_t)N;
  float* ad2  = W + o; o += (size_t)N;
  int* ip = (int*)(W + o);
  size_t io = 0;
  int* histA      = ip + io; io += (size_t)NB * B1;
  int* blockBase  = ip + io; io += (size_t)NB * B1;
  int* bucketBase = ip + io; io += NB + 1;
  int* rowptr     = ip + io; io += N + 1;
  int* csr_src    = ip + io; io += Etot;

  // CSR build: LDS-binned counting sort, no global return-atomics
  k_histA<<<B1, TPB, 0, stream>>>(ei, E, Etot, histA, NB, CH);
  k_scanA<<<1, TPB, 0, stream>>>(histA, blockBase, bucketBase, NB);
  k_placeB<<<B1, TPB, 0, stream>>>(ei, E, Etot, blockBase, bucketBase, pairs, NB, CH);
  k_bucket<<<NB, DPB, 0, stream>>>(pairs, bucketBase, rowptr, csr_src, N, Etot);

  // layer 1 + fused layer-2 linear
  k_gemm1<<<(N + 3) / 4, TPB, 0, stream>>>(x, W1, aS1, aD1, h1, as1, ad1, N);
  k_gather1f<<<(N + 3) / 4, TPB, 0, stream>>>(rowptr, csr_src, as1, ad1, h1, b1,
                                              W2, aS2, aD2, h2, as2, ad2, N);

  // layer 2 gather -> output
  k_gather2<<<(N * 64 + TPB - 1) / TPB, TPB, 0, stream>>>(rowptr, csr_src, as2, ad2, h2, b2, out, N);
}

// Round 11
// 137.421 us; speedup vs baseline: 1.1230x; 1.1230x over previous
//
#include <hip/hip_runtime.h>
#include <hip/hip_fp16.h>

#define TPB 256
#define NEG_SLOPE 0.2f
#define B1 256          // blocks for hist/place passes
#define DPB 512         // dsts per bucket
#define MAXNB 128       // max buckets

// ---------- helpers ----------
__device__ __forceinline__ int getIdx(const void* p, int is32, long long i) {
  return is32 ? ((const int*)p)[i] : (int)((const long long*)p)[i];
}

// ---------- CSR stage 1: per-block bucket histograms (inline dtype sniff) ----------
__global__ __launch_bounds__(TPB) void k_histA(
    const void* __restrict__ ei, int E, int Etot,
    int* __restrict__ histA, int NB, int CH) {
  __shared__ int lh[MAXNB];
  __shared__ int sflag;
  int b = blockIdx.x, tid = threadIdx.x;
  for (int i = tid; i < NB; i += TPB) lh[i] = 0;
  if (tid < 64) {  // wave 0: sniff int32 vs int64 storage (ids < 2^31)
    const unsigned long long* p = (const unsigned long long*)ei;
    unsigned long long m = __ballot(tid < E && p[tid] > 0xFFFFFFFFULL);
    if (tid == 0) sflag = (m != 0ULL) ? 1 : 0;
  }
  __syncthreads();
  int f = sflag;
  int beg = b * CH, end = min(beg + CH, Etot);
  for (int e = beg + tid; e < end; e += TPB) {
    int d = (e < E) ? getIdx(ei, f, (long long)E + e) : e - E;
    atomicAdd(&lh[d / DPB], 1);
  }
  __syncthreads();
  for (int i = tid; i < NB; i += TPB) histA[b * NB + i] = lh[i];  // [block][bucket]
}

// ---------- CSR stage 2: prefix bases (single block) ----------
__global__ __launch_bounds__(TPB) void k_scanA(
    const int* __restrict__ histA, int* __restrict__ blockBase,
    int* __restrict__ bucketBase, int NB) {
  __shared__ int sh[TPB];
  int t = threadIdx.x;
  int tot = 0;
  if (t < NB) {
    int run = 0;
    for (int b = 0; b < B1; ++b) {           // coalesced: histA[b*NB + t]
      int v = histA[b * NB + t];
      blockBase[b * NB + t] = run;           // intra-bucket prefix over blocks
      run += v;
    }
    tot = run;
  }
  sh[t] = tot;
  __syncthreads();
  for (int off = 1; off < TPB; off <<= 1) {
    int v = (t >= off) ? sh[t - off] : 0;
    __syncthreads();
    sh[t] += v;
    __syncthreads();
  }
  if (t < NB) bucketBase[t] = sh[t] - tot;   // exclusive
  if (t == TPB - 1) bucketBase[NB] = sh[TPB - 1];  // == Etot
}

// ---------- CSR stage 3: place (src,dst) int2 pairs grouped by bucket ----------
__global__ __launch_bounds__(TPB) void k_placeB(
    const void* __restrict__ ei, int E, int Etot,
    const int* __restrict__ blockBase, const int* __restrict__ bucketBase,
    int2* __restrict__ pairs, int NB, int CH) {
  __shared__ int cur[MAXNB];
  __shared__ int sflag;
  int b = blockIdx.x, tid = threadIdx.x;
  for (int i = tid; i < NB; i += TPB) cur[i] = blockBase[b * NB + i] + bucketBase[i];
  if (tid < 64) {
    const unsigned long long* p = (const unsigned long long*)ei;
    unsigned long long m = __ballot(tid < E && p[tid] > 0xFFFFFFFFULL);
    if (tid == 0) sflag = (m != 0ULL) ? 1 : 0;
  }
  __syncthreads();
  int f = sflag;
  int beg = b * CH, end = min(beg + CH, Etot);
  for (int e = beg + tid; e < end; e += TPB) {
    int s, d;
    if (e < E) {
      s = getIdx(ei, f, e);
      d = getIdx(ei, f, (long long)E + e);
    } else {
      s = d = e - E;
    }
    int pos = atomicAdd(&cur[d / DPB], 1);
    pairs[pos] = make_int2(s, d);
  }
}

// ---------- CSR stage 4: per-bucket hist+scan -> rowptr, then place csr_src ----------
__global__ __launch_bounds__(DPB) void k_bucket(
    const int2* __restrict__ pairs, const int* __restrict__ bucketBase,
    int* __restrict__ rowptr, int* __restrict__ csr_src, int N, int Etot) {
  __shared__ int cnt[DPB];
  __shared__ int sc[DPB];
  int g = blockIdx.x, tid = threadIdx.x;
  int base = g * DPB;
  int nd = N - base; if (nd > DPB) nd = DPB;
  cnt[tid] = 0;
  __syncthreads();
  int beg = bucketBase[g], end = bucketBase[g + 1];
  for (int j = beg + tid; j < end; j += DPB)
    atomicAdd(&cnt[pairs[j].y & (DPB - 1)], 1);
  __syncthreads();
  sc[tid] = cnt[tid];
  __syncthreads();
  for (int off = 1; off < DPB; off <<= 1) {
    int v = (tid >= off) ? sc[tid - off] : 0;
    __syncthreads();
    sc[tid] += v;
    __syncthreads();
  }
  int excl = beg + sc[tid] - cnt[tid];
  if (tid < nd) rowptr[base + tid] = excl;
  if (g == 0 && tid == 0) rowptr[N] = Etot;
  __syncthreads();
  cnt[tid] = excl;  // becomes cursor
  __syncthreads();
  for (int j = beg + tid; j < end; j += DPB) {
    int2 p = pairs[j];
    int pos = atomicAdd(&cnt[p.y & (DPB - 1)], 1);
    csr_src[pos] = p.x;
  }
}

// ---------- layer 1: h1 = x @ W1 (fp16 out), fused alpha dots ----------
__global__ __launch_bounds__(TPB) void k_gemm1(
    const float* __restrict__ x, const float* __restrict__ W1,
    const float* __restrict__ aS, const float* __restrict__ aD,
    __half* __restrict__ h1, float* __restrict__ asrc, float* __restrict__ adst, int N) {
  __shared__ float Wl[64 * 64];
  __shared__ float xr[4][64];
  int t = threadIdx.x;
  for (int i = t; i < 64 * 64; i += TPB) Wl[i] = W1[i];
  int w = t >> 6, lane = t & 63;
  int node = blockIdx.x * 4 + w;
  if (node < N) xr[w][lane] = x[(size_t)node * 64 + lane];
  __syncthreads();
  if (node >= N) return;
  float acc = 0.f;
#pragma unroll
  for (int k = 0; k < 64; ++k) acc = fmaf(xr[w][k], Wl[k * 64 + lane], acc);
  h1[(size_t)node * 64 + lane] = __float2half(acc);
  float vs = acc * aS[lane];
  float vd = acc * aD[lane];
#pragma unroll
  for (int m = 16; m >= 1; m >>= 1) {
    vs += __shfl_xor(vs, m, 64);
    vd += __shfl_xor(vd, m, 64);
  }
  if ((lane & 31) == 0) {
    asrc[node * 2 + (lane >> 5)] = vs;
    adst[node * 2 + (lane >> 5)] = vd;
  }
}

// ---------- fused layer-1 gather + layer-2 linear, batched-MLP schedule ----------
// Phase 1: lane i computes edge i's weights; staging zero-padded to 64 slots.
// Phase 2: 16 edges/iter, quarter-wave per edge, 4 manually-unrolled independent
//          8B gathers per lane -> 4+ loads in flight (vs ~1 with runtime loop).
__global__ __launch_bounds__(TPB) void k_gather1f(
    const int* __restrict__ rowptr, const int* __restrict__ csr_src,
    const float* __restrict__ as1, const float* __restrict__ ad1,
    const __half* __restrict__ h1, const float* __restrict__ b1,
    const float* __restrict__ W2, const float* __restrict__ aS2,
    const float* __restrict__ aD2,
    __half* __restrict__ h2, float* __restrict__ as2, float* __restrict__ ad2, int N) {
  __shared__ int   sSid[4][64];
  __shared__ float sWp[4][128];
  __shared__ float rowBuf[4][64];
  int t = threadIdx.x;
  int w = t >> 6, lane = t & 63;
  int node = blockIdx.x * 4 + w;
  if (node >= N) return;

  int e4 = lane >> 4, c4 = lane & 15;   // c4 owns halfs [c4*4, c4*4+4); e4 = edge slot
  int head = c4 >> 3;                   // head of those 4 feats
  float2 adv = *(const float2*)(ad1 + (size_t)node * 2);
  int beg = rowptr[node], end = rowptr[node + 1];
  float a0 = 0.f, a1 = 0.f, a2 = 0.f, a3 = 0.f, d0L = 0.f, d1L = 0.f;
  for (int chunk = beg; chunk < end; chunk += 64) {
    int m = end - chunk; if (m > 64) m = 64;
    int sid = 0; float w0 = 0.f, w1 = 0.f;   // zero-pad: wgt 0 contributes nothing
    if (lane < m) {                          // phase 1: up to 64 edges in parallel
      sid = csr_src[chunk + lane];
      float2 av = *(const float2*)(as1 + (size_t)sid * 2);
      float v0 = av.x + adv.x, v1 = av.y + adv.y;
      v0 = v0 > 0.f ? v0 : NEG_SLOPE * v0;
      v1 = v1 > 0.f ? v1 : NEG_SLOPE * v1;
      w0 = __expf(v0); w1 = __expf(v1);
      d0L += w0; d1L += w1;
    }
    sSid[w][lane] = sid;                     // unconditional: full 64-slot staging
    *(float2*)&sWp[w][lane * 2] = make_float2(w0, w1);
    // same-wave LDS handoff (lockstep, in-order LDS pipe)
    for (int j = 0; j < m; j += 16) {        // phase 2: 16 edges per iteration
      int j0 = j + e4, j1 = j0 + 4, j2 = j0 + 8, j3 = j0 + 12;
      int s0 = sSid[w][j0], s1 = sSid[w][j1], s2 = sSid[w][j2], s3 = sSid[w][j3];
      float q0 = sWp[w][j0 * 2 + head], q1 = sWp[w][j1 * 2 + head];
      float q2 = sWp[w][j2 * 2 + head], q3 = sWp[w][j3 * 2 + head];
      float2 r0 = *(const float2*)(h1 + (size_t)s0 * 64 + c4 * 4);
      float2 r1 = *(const float2*)(h1 + (size_t)s1 * 64 + c4 * 4);
      float2 r2 = *(const float2*)(h1 + (size_t)s2 * 64 + c4 * 4);
      float2 r3 = *(const float2*)(h1 + (size_t)s3 * 64 + c4 * 4);
      const __half2* p0 = (const __half2*)&r0;
      const __half2* p1 = (const __half2*)&r1;
      const __half2* p2 = (const __half2*)&r2;
      const __half2* p3 = (const __half2*)&r3;
      float2 u;
      u = __half22float2(p0[0]); a0 = fmaf(q0, u.x, a0); a1 = fmaf(q0, u.y, a1);
      u = __half22float2(p0[1]); a2 = fmaf(q0, u.x, a2); a3 = fmaf(q0, u.y, a3);
      u = __half22float2(p1[0]); a0 = fmaf(q1, u.x, a0); a1 = fmaf(q1, u.y, a1);
      u = __half22float2(p1[1]); a2 = fmaf(q1, u.x, a2); a3 = fmaf(q1, u.y, a3);
      u = __half22float2(p2[0]); a0 = fmaf(q2, u.x, a0); a1 = fmaf(q2, u.y, a1);
      u = __half22float2(p2[1]); a2 = fmaf(q2, u.x, a2); a3 = fmaf(q2, u.y, a3);
      u = __half22float2(p3[0]); a0 = fmaf(q3, u.x, a0); a1 = fmaf(q3, u.y, a1);
      u = __half22float2(p3[1]); a2 = fmaf(q3, u.x, a2); a3 = fmaf(q3, u.y, a3);
    }
  }
  // combine the 4 edge-slot groups
#pragma unroll
  for (int m2 = 16; m2 <= 32; m2 <<= 1) {
    a0 += __shfl_xor(a0, m2, 64);
    a1 += __shfl_xor(a1, m2, 64);
    a2 += __shfl_xor(a2, m2, 64);
    a3 += __shfl_xor(a3, m2, 64);
  }
#pragma unroll
  for (int m2 = 1; m2 <= 32; m2 <<= 1) {  // denominator: full-wave reduce
    d0L += __shfl_xor(d0L, m2, 64);
    d1L += __shfl_xor(d1L, m2, 64);
  }
  float inv = 1.f / ((head == 0 ? d0L : d1L) + 1e-16f);
  float4 b1v = ((const float4*)b1)[c4];
  float o0 = fmaf(a0, inv, b1v.x);
  float o1 = fmaf(a1, inv, b1v.y);
  float o2 = fmaf(a2, inv, b1v.z);
  float o3 = fmaf(a3, inv, b1v.w);
  o0 = o0 > 0.f ? o0 : 0.f;
  o1 = o1 > 0.f ? o1 : 0.f;
  o2 = o2 > 0.f ? o2 : 0.f;
  o3 = o3 > 0.f ? o3 : 0.f;
  if (e4 == 0) *(float4*)&rowBuf[w][c4 * 4] = make_float4(o0, o1, o2, o3);
  // layer-2 dot: W2 in registers (L1-hot), row broadcast from LDS (b128)
  int c = lane & 31, eh = lane >> 5;
  float w2r[32];
#pragma unroll
  for (int k = 0; k < 32; ++k) w2r[k] = W2[(eh * 32 + k) * 32 + c];
  float acc2 = 0.f;
#pragma unroll
  for (int kk = 0; kk < 8; ++kk) {
    float4 rv = *(const float4*)&rowBuf[w][eh * 32 + kk * 4];
    acc2 = fmaf(rv.x, w2r[kk * 4 + 0], acc2);
    acc2 = fmaf(rv.y, w2r[kk * 4 + 1], acc2);
    acc2 = fmaf(rv.z, w2r[kk * 4 + 2], acc2);
    acc2 = fmaf(rv.w, w2r[kk * 4 + 3], acc2);
  }
  acc2 += __shfl_xor(acc2, 32, 64);      // combine k-range halves
  if (eh == 0) h2[(size_t)node * 32 + c] = __float2half(acc2);
  float vs = acc2 * aS2[c];
  float vd = acc2 * aD2[c];
#pragma unroll
  for (int m2 = 16; m2 >= 1; m2 >>= 1) {
    vs += __shfl_xor(vs, m2, 64);
    vd += __shfl_xor(vd, m2, 64);
  }
  if (lane == 0) {
    as2[node] = vs;
    ad2[node] = vd;
  }
}

// ---------- layer 2 gather: batched-MLP, 32 edges/iter, 8-lane group per edge ----------
__global__ __launch_bounds__(TPB) void k_gather2(
    const int* __restrict__ rowptr, const int* __restrict__ csr_src,
    const float* __restrict__ as2, const float* __restrict__ ad2,
    const __half* __restrict__ h2, const float* __restrict__ b,
    float* __restrict__ out, int N) {
  __shared__ int   sS[4][64];
  __shared__ float sWv[4][64];
  int t = threadIdx.x;
  int w = t >> 6;
  int wid = (int)((blockIdx.x * (unsigned)TPB + t) >> 6);
  int lane = t & 63;
  if (wid >= N) return;
  int e8 = lane >> 3, c8 = lane & 7;   // c8 owns halfs [c8*4, c8*4+4); e8 = edge slot
  float ad = ad2[wid];
  int beg = rowptr[wid], end = rowptr[wid + 1];
  float a0 = 0.f, a1 = 0.f, a2 = 0.f, a3 = 0.f, dL = 0.f;
  for (int chunk = beg; chunk < end; chunk += 64) {
    int m = end - chunk; if (m > 64) m = 64;
    int sid = 0; float wv = 0.f;
    if (lane < m) {                      // phase 1
      sid = csr_src[chunk + lane];
      float v = as2[sid] + ad;
      v = v > 0.f ? v : NEG_SLOPE * v;
      wv = __expf(v);
      dL += wv;
    }
    sS[w][lane] = sid;
    sWv[w][lane] = wv;
    for (int j = 0; j < m; j += 32) {    // phase 2: 32 edges per iteration
      int j0 = j + e8, j1 = j0 + 8, j2 = j0 + 16, j3 = j0 + 24;
      int s0 = sS[w][j0], s1 = sS[w][j1], s2 = sS[w][j2], s3 = sS[w][j3];
      float q0 = sWv[w][j0], q1 = sWv[w][j1], q2 = sWv[w][j2], q3 = sWv[w][j3];
      float2 r0 = *(const float2*)(h2 + (size_t)s0 * 32 + c8 * 4);
      float2 r1 = *(const float2*)(h2 + (size_t)s1 * 32 + c8 * 4);
      float2 r2 = *(const float2*)(h2 + (size_t)s2 * 32 + c8 * 4);
      float2 r3 = *(const float2*)(h2 + (size_t)s3 * 32 + c8 * 4);
      const __half2* p0 = (const __half2*)&r0;
      const __half2* p1 = (const __half2*)&r1;
      const __half2* p2 = (const __half2*)&r2;
      const __half2* p3 = (const __half2*)&r3;
      float2 u;
      u = __half22float2(p0[0]); a0 = fmaf(q0, u.x, a0); a1 = fmaf(q0, u.y, a1);
      u = __half22float2(p0[1]); a2 = fmaf(q0, u.x, a2); a3 = fmaf(q0, u.y, a3);
      u = __half22float2(p1[0]); a0 = fmaf(q1, u.x, a0); a1 = fmaf(q1, u.y, a1);
      u = __half22float2(p1[1]); a2 = fmaf(q1, u.x, a2); a3 = fmaf(q1, u.y, a3);
      u = __half22float2(p2[0]); a0 = fmaf(q2, u.x, a0); a1 = fmaf(q2, u.y, a1);
      u = __half22float2(p2[1]); a2 = fmaf(q2, u.x, a2); a3 = fmaf(q2, u.y, a3);
      u = __half22float2(p3[0]); a0 = fmaf(q3, u.x, a0); a1 = fmaf(q3, u.y, a1);
      u = __half22float2(p3[1]); a2 = fmaf(q3, u.x, a2); a3 = fmaf(q3, u.y, a3);
    }
  }
#pragma unroll
  for (int m2 = 8; m2 <= 32; m2 <<= 1) {  // combine the 8 edge-slot groups
    a0 += __shfl_xor(a0, m2, 64);
    a1 += __shfl_xor(a1, m2, 64);
    a2 += __shfl_xor(a2, m2, 64);
    a3 += __shfl_xor(a3, m2, 64);
  }
#pragma unroll
  for (int m2 = 1; m2 <= 32; m2 <<= 1) dL += __shfl_xor(dL, m2, 64);
  if (e8 == 0) {
    float inv = 1.f / (dL + 1e-16f);
    float4 bv = ((const float4*)b)[c8];
    float4 o;
    o.x = fmaf(a0, inv, bv.x);
    o.y = fmaf(a1, inv, bv.y);
    o.z = fmaf(a2, inv, bv.z);
    o.w = fmaf(a3, inv, bv.w);
    *(float4*)(out + (size_t)wid * 32 + c8 * 4) = o;
  }
}

extern "C" void kernel_launch(void* const* d_in, const int* in_sizes, int n_in,
                              void* d_out, int out_size, void* d_ws, size_t ws_size,
                              hipStream_t stream) {
  const float* x   = (const float*)d_in[0];
  const void*  ei  = d_in[1];
  const float* W1  = (const float*)d_in[2];
  const float* aS1 = (const float*)d_in[3];
  const float* aD1 = (const float*)d_in[4];
  const float* b1  = (const float*)d_in[5];
  const float* W2  = (const float*)d_in[6];
  const float* aS2 = (const float*)d_in[7];
  const float* aD2 = (const float*)d_in[8];
  const float* b2  = (const float*)d_in[9];
  float* out = (float*)d_out;

  int N = in_sizes[0] / 64;
  int E = in_sizes[1] / 2;
  int Etot = E + N;
  int NB = (N + DPB - 1) / DPB;         // dst buckets
  int CH = (Etot + B1 - 1) / B1;        // edges per hist/place block

  float* W = (float*)d_ws;
  size_t o = 0;
  __half* h1 = (__half*)(W + o); o += (size_t)N * 32;   // N*64 halfs
  // pairs (int2, Etot) shares storage with h2 (N*32 halfs): disjoint lifetimes
  size_t regB = (size_t)(2 * (size_t)Etot > (size_t)N * 16 ? 2 * (size_t)Etot : (size_t)N * 16);
  int2* pairs = (int2*)(W + o);
  __half* h2  = (__half*)(W + o);
  o += regB;
  float* as1  = W + o; o += (size_t)N * 2;
  float* ad1  = W + o; o += (size_t)N * 2;
  float* as2  = W + o; o += (size_t)N;
  float* ad2  = W + o; o += (size_t)N;
  int* ip = (int*)(W + o);
  size_t io = 0;
  int* histA      = ip + io; io += (size_t)NB * B1;
  int* blockBase  = ip + io; io += (size_t)NB * B1;
  int* bucketBase = ip + io; io += NB + 1;
  int* rowptr     = ip + io; io += N + 1;
  int* csr_src    = ip + io; io += Etot;

  // CSR build: LDS-binned counting sort, no global return-atomics
  k_histA<<<B1, TPB, 0, stream>>>(ei, E, Etot, histA, NB, CH);
  k_scanA<<<1, TPB, 0, stream>>>(histA, blockBase, bucketBase, NB);
  k_placeB<<<B1, TPB, 0, stream>>>(ei, E, Etot, blockBase, bucketBase, pairs, NB, CH);
  k_bucket<<<NB, DPB, 0, stream>>>(pairs, bucketBase, rowptr, csr_src, N, Etot);

  // layer 1 + fused layer-2 linear
  k_gemm1<<<(N + 3) / 4, TPB, 0, stream>>>(x, W1, aS1, aD1, h1, as1, ad1, N);
  k_gather1f<<<(N + 3) / 4, TPB, 0, stream>>>(rowptr, csr_src, as1, ad1, h1, b1,
                                              W2, aS2, aD2, h2, as2, ad2, N);

  // layer 2 gather -> output
  k_gather2<<<(N * 64 + TPB - 1) / TPB, TPB, 0, stream>>>(rowptr, csr_src, as2, ad2, h2, b2, out, N);
}